// Round 4
// baseline (11274.173 us; speedup 1.0000x reference)
//
#include <hip/hip_runtime.h>
#include <stdint.h>

// Codec forward: encoder GEMMs (f32, tanh) -> 4x VQ (exact JAX threefry noise,
// argmax, codebook gather) -> decoder GEMMs (f32).
// Round 3 fix: JAX >=0.5 defaults jax_threefry_partitionable=True.
// random_bits(key, 32, shape) = o1 ^ o2 where (o1,o2) = threefry2x32(key,
// (i>>32, i&0xffffffff)) per flat element i  — NOT the legacy split-half iota.

#define IMG_DIM 3072
#define HID     16384
#define NCODE   256
#define DCODE   64

// ---------------- Threefry2x32 (matches jax/_src/prng.py) ----------------
__host__ __device__ __forceinline__ uint32_t rotl32(uint32_t v, int d) {
    return (v << d) | (v >> (32 - d));
}

__host__ __device__ __forceinline__ void tf2x32(uint32_t k0, uint32_t k1,
                                                uint32_t& x0, uint32_t& x1) {
    uint32_t k2 = k0 ^ k1 ^ 0x1BD11BDAu;
    x0 += k0; x1 += k1;
    x0 += x1; x1 = rotl32(x1, 13); x1 ^= x0;
    x0 += x1; x1 = rotl32(x1, 15); x1 ^= x0;
    x0 += x1; x1 = rotl32(x1, 26); x1 ^= x0;
    x0 += x1; x1 = rotl32(x1,  6); x1 ^= x0;
    x0 += k1; x1 += k2 + 1u;
    x0 += x1; x1 = rotl32(x1, 17); x1 ^= x0;
    x0 += x1; x1 = rotl32(x1, 29); x1 ^= x0;
    x0 += x1; x1 = rotl32(x1, 16); x1 ^= x0;
    x0 += x1; x1 = rotl32(x1, 24); x1 ^= x0;
    x0 += k2; x1 += k0 + 2u;
    x0 += x1; x1 = rotl32(x1, 13); x1 ^= x0;
    x0 += x1; x1 = rotl32(x1, 15); x1 ^= x0;
    x0 += x1; x1 = rotl32(x1, 26); x1 ^= x0;
    x0 += x1; x1 = rotl32(x1,  6); x1 ^= x0;
    x0 += k0; x1 += k1 + 3u;
    x0 += x1; x1 = rotl32(x1, 17); x1 ^= x0;
    x0 += x1; x1 = rotl32(x1, 29); x1 ^= x0;
    x0 += x1; x1 = rotl32(x1, 16); x1 ^= x0;
    x0 += x1; x1 = rotl32(x1, 24); x1 ^= x0;
    x0 += k1; x1 += k2 + 4u;
    x0 += x1; x1 = rotl32(x1, 13); x1 ^= x0;
    x0 += x1; x1 = rotl32(x1, 15); x1 ^= x0;
    x0 += x1; x1 = rotl32(x1, 26); x1 ^= x0;
    x0 += x1; x1 = rotl32(x1,  6); x1 ^= x0;
    x0 += k2; x1 += k0 + 5u;
}

// ---------------- f32 tiled GEMM: C = act(A @ W[:K] + W[K]) ----------------
// A: [M,K] row-major; W: [K+1,N] row-major (last row = bias); C: [M,N].
template <int BM, int BN, bool TANH>
__global__ __launch_bounds__(256) void gemm_f32(const float* __restrict__ A,
                                                const float* __restrict__ W,
                                                float* __restrict__ C,
                                                int M, int N, int K) {
    constexpr int BK = 16;
    constexpr int TM = BM / 16, TN = BN / 16;
    constexpr int GM = TM / 4, GN = TN / 4;
    constexpr int PA = BM + 4, PB = BN + 4;   // pad to kill bank conflicts, keep 16B align
    __shared__ float As[BK][PA];              // stored transposed: As[k][m]
    __shared__ float Bs[BK][PB];

    const int tid = threadIdx.x;
    const int tx = tid & 15, ty = tid >> 4;
    const size_t bm = (size_t)blockIdx.y * BM;
    const size_t bn = (size_t)blockIdx.x * BN;

    float acc[TM][TN];
#pragma unroll
    for (int i = 0; i < TM; ++i)
#pragma unroll
        for (int j = 0; j < TN; ++j) acc[i][j] = 0.f;

    for (int k0 = 0; k0 < K; k0 += BK) {
        // A tile: [BM][BK] -> transposed into As[k][m]
#pragma unroll
        for (int i = 0; i < BM * BK / 4 / 256; ++i) {
            int f4 = tid + i * 256;
            int row = f4 >> 2;          // BK/4 == 4
            int c4 = f4 & 3;
            float4 v = *reinterpret_cast<const float4*>(A + (bm + row) * K + k0 + c4 * 4);
            As[c4 * 4 + 0][row] = v.x;
            As[c4 * 4 + 1][row] = v.y;
            As[c4 * 4 + 2][row] = v.z;
            As[c4 * 4 + 3][row] = v.w;
        }
        // B tile: [BK][BN]
#pragma unroll
        for (int i = 0; i < BK * BN / 4 / 256; ++i) {
            int f4 = tid + i * 256;
            int row = f4 / (BN / 4);
            int c4 = f4 % (BN / 4);
            *reinterpret_cast<float4*>(&Bs[row][c4 * 4]) =
                *reinterpret_cast<const float4*>(W + (size_t)(k0 + row) * N + bn + c4 * 4);
        }
        __syncthreads();
#pragma unroll
        for (int k = 0; k < BK; ++k) {
            float4 af[GM], bf[GN];
#pragma unroll
            for (int g = 0; g < GM; ++g)
                af[g] = *reinterpret_cast<const float4*>(&As[k][g * 64 + ty * 4]);
#pragma unroll
            for (int g = 0; g < GN; ++g)
                bf[g] = *reinterpret_cast<const float4*>(&Bs[k][g * 64 + tx * 4]);
#pragma unroll
            for (int gm = 0; gm < GM; ++gm) {
                const float* ap = &af[gm].x;
#pragma unroll
                for (int r = 0; r < 4; ++r) {
#pragma unroll
                    for (int gn = 0; gn < GN; ++gn) {
                        const float* bp = &bf[gn].x;
#pragma unroll
                        for (int c = 0; c < 4; ++c)
                            acc[gm * 4 + r][gn * 4 + c] =
                                fmaf(ap[r], bp[c], acc[gm * 4 + r][gn * 4 + c]);
                    }
                }
            }
        }
        __syncthreads();
    }

    // epilogue: bias (+ tanh) + store
#pragma unroll
    for (int gm = 0; gm < GM; ++gm) {
#pragma unroll
        for (int r = 0; r < 4; ++r) {
            size_t row = bm + gm * 64 + ty * 4 + r;
#pragma unroll
            for (int gn = 0; gn < GN; ++gn) {
                size_t col = bn + gn * 64 + tx * 4;
                float4 bias = *reinterpret_cast<const float4*>(W + (size_t)K * N + col);
                float4 o;
                o.x = acc[gm * 4 + r][gn * 4 + 0] + bias.x;
                o.y = acc[gm * 4 + r][gn * 4 + 1] + bias.y;
                o.z = acc[gm * 4 + r][gn * 4 + 2] + bias.z;
                o.w = acc[gm * 4 + r][gn * 4 + 3] + bias.w;
                if (TANH) {
                    o.x = tanhf(o.x); o.y = tanhf(o.y);
                    o.z = tanhf(o.z); o.w = tanhf(o.w);
                }
                *reinterpret_cast<float4*>(C + row * N + col) = o;
            }
        }
    }
}

// ---------------- VQ: distances -> softmax -> noise -> argmax -> gather ----
// One block per (row b, chunk). 256 threads = one code each.
__global__ __launch_bounds__(256) void vq_kernel(
    const float* __restrict__ h,   // [B, 256]
    const float* __restrict__ cb,  // [256, 64]
    const uint32_t* __restrict__ nlp,  // noise_level scalar (int32 OR f32 bits)
    float* __restrict__ y,         // [B, 256]
    uint32_t ka0, uint32_t ka1, uint32_t kb0, uint32_t kb1,
    uint32_t kc0, uint32_t kc1, uint32_t kd0, uint32_t kd1) {
    __shared__ float xs[DCODE];
    __shared__ float sred[NCODE];
    __shared__ int sidx[NCODE];

    const int b = blockIdx.x;
    const int chunk = blockIdx.y;
    const int c = threadIdx.x;

    if (c < DCODE) xs[c] = h[(size_t)b * NCODE + chunk * DCODE + c];
    __syncthreads();

    float dot = 0.f, x2 = 0.f, c2 = 0.f;
    const float* crow = cb + c * DCODE;
#pragma unroll 8
    for (int i = 0; i < DCODE; ++i) {
        float xv = xs[i], cv = crow[i];
        dot = fmaf(xv, cv, dot);
        x2 = fmaf(xv, xv, x2);
        c2 = fmaf(cv, cv, c2);
    }
    float d = sqrtf(fmaxf(x2 - 2.f * dot + c2, 0.f));
    float logit = -d * 0.125f;  // -d / sqrt(64)

    // softmax max-reduce
    sred[c] = logit;
    __syncthreads();
    for (int s = 128; s > 0; s >>= 1) {
        if (c < s) sred[c] = fmaxf(sred[c], sred[c + s]);
        __syncthreads();
    }
    float mx = sred[0];
    __syncthreads();
    float e = expf(logit - mx);
    sred[c] = e;
    __syncthreads();
    for (int s = 128; s > 0; s >>= 1) {
        if (c < s) sred[c] = sred[c] + sred[c + s];
        __syncthreads();
    }
    float ssum = sred[0];
    __syncthreads();
    float r = e / ssum;

    // noise_level: dtype-agnostic scalar read.
    int vi = (int)nlp[0];
    float noise_level = (vi >= -1000000 && vi <= 1000000)
                            ? (float)vi
                            : __uint_as_float(nlp[0]);

    // JAX partitionable threefry random bits (jax >= 0.5 default):
    // per flat element i of [B,256]: (o1,o2) = threefry2x32(key, (i>>32, i&0xffffffff));
    // bits = o1 ^ o2.  Our size < 2^32 so hi word is 0.
    uint32_t lin = (uint32_t)b * 256u + (uint32_t)c;
    uint32_t k0 = chunk == 0 ? ka0 : chunk == 1 ? kb0 : chunk == 2 ? kc0 : kd0;
    uint32_t k1 = chunk == 0 ? ka1 : chunk == 1 ? kb1 : chunk == 2 ? kc1 : kd1;
    uint32_t x0 = 0u, x1 = lin;
    tf2x32(k0, k1, x0, x1);
    uint32_t bits = x0 ^ x1;
    float noise = __uint_as_float((bits >> 9) | 0x3f800000u) - 1.0f;

    float score = r - noise_level * noise;

    // argmax, first-index tiebreak
    sred[c] = score;
    sidx[c] = c;
    __syncthreads();
    for (int s = 128; s > 0; s >>= 1) {
        if (c < s) {
            float ov = sred[c + s];
            int oi = sidx[c + s];
            if (ov > sred[c] || (ov == sred[c] && oi < sidx[c])) {
                sred[c] = ov;
                sidx[c] = oi;
            }
        }
        __syncthreads();
    }
    int best = sidx[0];

    if (c < DCODE) y[(size_t)b * NCODE + chunk * DCODE + c] = cb[(size_t)best * DCODE + c];
}

// ---------------- launch ----------------
extern "C" void kernel_launch(void* const* d_in, const int* in_sizes, int n_in,
                              void* d_out, int out_size, void* d_ws, size_t ws_size,
                              hipStream_t stream) {
    const float* x   = (const float*)d_in[0];
    const float* w1e = (const float*)d_in[1];
    const float* w2e = (const float*)d_in[2];
    const float* w1d = (const float*)d_in[3];
    const float* w2d = (const float*)d_in[4];
    const float* cb1 = (const float*)d_in[5];
    const uint32_t* nl = (const uint32_t*)d_in[9];
    float* out = (float*)d_out;

    const int M = in_sizes[0] / IMG_DIM;  // 4096

    // workspace: h1/d1 share one [M,HID] buffer; h,y are [M,256]
    float* h1 = (float*)d_ws;
    float* h  = h1 + (size_t)M * HID;
    float* yb = h + (size_t)M * NCODE;

    // encoder 1: tanh(x @ w1e + b)
    {
        dim3 g(HID / 128, M / 128);
        gemm_f32<128, 128, true><<<g, 256, 0, stream>>>(x, w1e, h1, M, HID, IMG_DIM);
    }
    // encoder 2: tanh(h1 @ w2e + b) -> [M,256]
    {
        dim3 g(NCODE / 64, M / 64);
        gemm_f32<64, 64, true><<<g, 256, 0, stream>>>(h1, w2e, h, M, NCODE, HID);
    }
    // VQ (keys: fold_in(key(12345), j) for j=1..4, computed host-side;
    //  fold_in uses raw threefry_2x32 on [0, j] — unaffected by partitionable)
    {
        uint32_t ks[4][2];
        for (int j = 1; j <= 4; ++j) {
            uint32_t a = 0u, bb = (uint32_t)j;
            tf2x32(0u, 12345u, a, bb);
            ks[j - 1][0] = a;
            ks[j - 1][1] = bb;
        }
        dim3 g(M, 4);
        vq_kernel<<<g, 256, 0, stream>>>(h, cb1, nl, yb,
                                         ks[0][0], ks[0][1], ks[1][0], ks[1][1],
                                         ks[2][0], ks[2][1], ks[3][0], ks[3][1]);
    }
    // decoder 1: tanh(y @ w1d + b) -> reuse h1
    {
        dim3 g(HID / 128, M / 128);
        gemm_f32<128, 128, true><<<g, 256, 0, stream>>>(yb, w1d, h1, M, HID, NCODE);
    }
    // decoder 2: h1 @ w2d + b -> out
    {
        dim3 g(IMG_DIM / 128, M / 128);
        gemm_f32<128, 128, false><<<g, 256, 0, stream>>>(h1, w2d, out, M, IMG_DIM, HID);
    }
}

// Round 6
// 3088.416 us; speedup vs baseline: 3.6505x; 3.6505x over previous
//
#include <hip/hip_runtime.h>
#include <stdint.h>

// Codec forward. Round 4: MFMA pipeline.
//   encoder: bf16x2-split 3-term MFMA (argmax-safe, rel err ~2^-17)
//   decoder: plain bf16 MFMA (absmax threshold 0.0734 tolerates 2^-9)
//   weights pre-transposed+converted to [N][K] bf16 in d_ws each call.
// Falls back to the verified f32-VALU path if ws_size is too small.
// Round 5: resubmit unchanged (container infra failure, no signal).

#define IMG_DIM 3072
#define HID     16384
#define NCODE   256
#define DCODE   64

typedef short bf16x8 __attribute__((ext_vector_type(8)));
typedef float f32x4 __attribute__((ext_vector_type(4)));

__device__ __forceinline__ uint16_t bf16rne(float f) {
    uint32_t u = __float_as_uint(f);
    return (uint16_t)((u + 0x7fffu + ((u >> 16) & 1u)) >> 16);
}
__device__ __forceinline__ float b2f(uint16_t h) {
    return __uint_as_float((uint32_t)h << 16);
}

#define GLLDS(g, l)                                                        \
    __builtin_amdgcn_global_load_lds(                                      \
        (const __attribute__((address_space(1))) uint32_t*)(const void*)(g), \
        (__attribute__((address_space(3))) uint32_t*)(void*)(l), 16, 0, 0)

// ---------------- Threefry2x32 (matches jax/_src/prng.py) ----------------
__host__ __device__ __forceinline__ uint32_t rotl32(uint32_t v, int d) {
    return (v << d) | (v >> (32 - d));
}

__host__ __device__ __forceinline__ void tf2x32(uint32_t k0, uint32_t k1,
                                                uint32_t& x0, uint32_t& x1) {
    uint32_t k2 = k0 ^ k1 ^ 0x1BD11BDAu;
    x0 += k0; x1 += k1;
    x0 += x1; x1 = rotl32(x1, 13); x1 ^= x0;
    x0 += x1; x1 = rotl32(x1, 15); x1 ^= x0;
    x0 += x1; x1 = rotl32(x1, 26); x1 ^= x0;
    x0 += x1; x1 = rotl32(x1,  6); x1 ^= x0;
    x0 += k1; x1 += k2 + 1u;
    x0 += x1; x1 = rotl32(x1, 17); x1 ^= x0;
    x0 += x1; x1 = rotl32(x1, 29); x1 ^= x0;
    x0 += x1; x1 = rotl32(x1, 16); x1 ^= x0;
    x0 += x1; x1 = rotl32(x1, 24); x1 ^= x0;
    x0 += k2; x1 += k0 + 2u;
    x0 += x1; x1 = rotl32(x1, 13); x1 ^= x0;
    x0 += x1; x1 = rotl32(x1, 15); x1 ^= x0;
    x0 += x1; x1 = rotl32(x1, 26); x1 ^= x0;
    x0 += x1; x1 = rotl32(x1,  6); x1 ^= x0;
    x0 += k0; x1 += k1 + 3u;
    x0 += x1; x1 = rotl32(x1, 17); x1 ^= x0;
    x0 += x1; x1 = rotl32(x1, 29); x1 ^= x0;
    x0 += x1; x1 = rotl32(x1, 16); x1 ^= x0;
    x0 += x1; x1 = rotl32(x1, 24); x1 ^= x0;
    x0 += k1; x1 += k2 + 4u;
    x0 += x1; x1 = rotl32(x1, 13); x1 ^= x0;
    x0 += x1; x1 = rotl32(x1, 15); x1 ^= x0;
    x0 += x1; x1 = rotl32(x1, 26); x1 ^= x0;
    x0 += x1; x1 = rotl32(x1,  6); x1 ^= x0;
    x0 += k2; x1 += k0 + 5u;
}

// ---------------- MFMA GEMM: C = act(A @ B^T_layout + bias) ----------------
// A: bf16 [M][K] (hi, + lo if SPLIT); B: bf16 [N][K] (pre-transposed weights).
// 128x128 tile, BK=32, 4 waves (2x2), each wave 64x64 via 4x4 16x16x32 MFMAs.
// EPI: 0 = f32 out; 1 = f32 tanh; 2 = bf16 tanh; 3 = bf16 hi/lo tanh.
template <int EPI, bool SPLIT>
__global__ __launch_bounds__(256) void gemm_mfma(
    const uint16_t* __restrict__ Ahi, const uint16_t* __restrict__ Alo,
    const uint16_t* __restrict__ Bhi, const uint16_t* __restrict__ Blo,
    const float* __restrict__ biasp,
    float* __restrict__ Cf, uint16_t* __restrict__ Cb,
    uint16_t* __restrict__ Chi, uint16_t* __restrict__ Clo,
    int M, int N, int K) {
    constexpr int AT = 128 * 32;  // uint16 elements per tile
    __shared__ __align__(16) uint16_t As[SPLIT ? 2 * AT : AT];
    __shared__ __align__(16) uint16_t Bs[SPLIT ? 2 * AT : AT];

    const int tid = threadIdx.x;
    const int lane = tid & 63, wv = tid >> 6;
    const int wm = wv >> 1, wn = wv & 1;
    const int la = lane & 15, lk = lane >> 4;
    const size_t bm = (size_t)blockIdx.y * 128, bn = (size_t)blockIdx.x * 128;

    f32x4 acc[4][4];
#pragma unroll
    for (int i = 0; i < 4; ++i)
#pragma unroll
        for (int j = 0; j < 4; ++j) acc[i][j] = (f32x4){0.f, 0.f, 0.f, 0.f};

    for (int k0 = 0; k0 < K; k0 += 32) {
        // stage tiles: [128 rows][32 k] bf16, linear, via global_load_lds 16B
#pragma unroll
        for (int t = 0; t < 2; ++t) {
            const int cb_ = wv * 128 + t * 64;  // wave-uniform chunk base
            const int c = cb_ + lane;
            const int row = c >> 2, sub = c & 3;
            GLLDS(Ahi + (bm + row) * (size_t)K + k0 + sub * 8, &As[(size_t)cb_ * 8]);
            GLLDS(Bhi + (bn + row) * (size_t)K + k0 + sub * 8, &Bs[(size_t)cb_ * 8]);
            if constexpr (SPLIT) {
                GLLDS(Alo + (bm + row) * (size_t)K + k0 + sub * 8, &As[AT + (size_t)cb_ * 8]);
                GLLDS(Blo + (bn + row) * (size_t)K + k0 + sub * 8, &Bs[AT + (size_t)cb_ * 8]);
            }
        }
        __syncthreads();

        bf16x8 ah[4], bh[4], al[4], bl[4];
#pragma unroll
        for (int i = 0; i < 4; ++i) {
            const int ao = (wm * 64 + i * 16 + la) * 32 + lk * 8;
            const int bo = (wn * 64 + i * 16 + la) * 32 + lk * 8;
            ah[i] = *(const bf16x8*)&As[ao];
            bh[i] = *(const bf16x8*)&Bs[bo];
            if constexpr (SPLIT) {
                al[i] = *(const bf16x8*)&As[AT + ao];
                bl[i] = *(const bf16x8*)&Bs[AT + bo];
            }
        }
#pragma unroll
        for (int i = 0; i < 4; ++i)
#pragma unroll
            for (int j = 0; j < 4; ++j) {
                acc[i][j] = __builtin_amdgcn_mfma_f32_16x16x32_bf16(ah[i], bh[j], acc[i][j], 0, 0, 0);
                if constexpr (SPLIT) {
                    acc[i][j] = __builtin_amdgcn_mfma_f32_16x16x32_bf16(al[i], bh[j], acc[i][j], 0, 0, 0);
                    acc[i][j] = __builtin_amdgcn_mfma_f32_16x16x32_bf16(ah[i], bl[j], acc[i][j], 0, 0, 0);
                }
            }
        __syncthreads();
    }

    // epilogue: C row = bm+wm*64+i*16+lk*4+r, col = bn+wn*64+j*16+la
    const int colb = (int)bn + wn * 64 + la;
    float bj[4];
#pragma unroll
    for (int j = 0; j < 4; ++j) bj[j] = biasp[colb + j * 16];
#pragma unroll
    for (int i = 0; i < 4; ++i) {
        const int rb = (int)bm + wm * 64 + i * 16 + lk * 4;
#pragma unroll
        for (int j = 0; j < 4; ++j) {
            const int col = colb + j * 16;
#pragma unroll
            for (int r = 0; r < 4; ++r) {
                float v = acc[i][j][r] + bj[j];
                const size_t idx = (size_t)(rb + r) * N + col;
                if constexpr (EPI == 0) Cf[idx] = v;
                if constexpr (EPI == 1) Cf[idx] = tanhf(v);
                if constexpr (EPI == 2) Cb[idx] = bf16rne(tanhf(v));
                if constexpr (EPI == 3) {
                    float tv = tanhf(v);
                    uint16_t h = bf16rne(tv);
                    Chi[idx] = h;
                    Clo[idx] = bf16rne(tv - b2f(h));
                }
            }
        }
    }
}

// ---------------- weight transpose+convert: W f32 [K+1][N] -> [N][K] bf16 ----
template <bool SPLIT>
__global__ __launch_bounds__(256) void wconv(const float* __restrict__ W,
                                             uint16_t* __restrict__ Thi,
                                             uint16_t* __restrict__ Tlo,
                                             int K, int N) {
    __shared__ float t[32][33];
    const int k0 = blockIdx.x * 32, n0 = blockIdx.y * 32;
    const int tid = threadIdx.x;
    {
        const int kl = tid >> 3, nq = tid & 7;
        float4 v = *(const float4*)(W + (size_t)(k0 + kl) * N + n0 + nq * 4);
        t[kl][nq * 4 + 0] = v.x;
        t[kl][nq * 4 + 1] = v.y;
        t[kl][nq * 4 + 2] = v.z;
        t[kl][nq * 4 + 3] = v.w;
    }
    __syncthreads();
    {
        const int nl = tid >> 3, kq = tid & 7;
        ushort4 hv, lv;
        float f0 = t[kq * 4 + 0][nl], f1 = t[kq * 4 + 1][nl];
        float f2 = t[kq * 4 + 2][nl], f3 = t[kq * 4 + 3][nl];
        hv.x = bf16rne(f0); hv.y = bf16rne(f1); hv.z = bf16rne(f2); hv.w = bf16rne(f3);
        *(ushort4*)(Thi + (size_t)(n0 + nl) * K + k0 + kq * 4) = hv;
        if constexpr (SPLIT) {
            lv.x = bf16rne(f0 - b2f(hv.x)); lv.y = bf16rne(f1 - b2f(hv.y));
            lv.z = bf16rne(f2 - b2f(hv.z)); lv.w = bf16rne(f3 - b2f(hv.w));
            *(ushort4*)(Tlo + (size_t)(n0 + nl) * K + k0 + kq * 4) = lv;
        }
    }
}

// ---------------- x -> hi/lo bf16 split (elementwise) ----------------
__global__ __launch_bounds__(256) void split_x(const float* __restrict__ x,
                                               uint16_t* __restrict__ hi,
                                               uint16_t* __restrict__ lo,
                                               size_t n4) {
    for (size_t i = (size_t)blockIdx.x * 256 + threadIdx.x; i < n4;
         i += (size_t)gridDim.x * 256) {
        float4 v = ((const float4*)x)[i];
        ushort4 h, l;
        h.x = bf16rne(v.x); l.x = bf16rne(v.x - b2f(h.x));
        h.y = bf16rne(v.y); l.y = bf16rne(v.y - b2f(h.y));
        h.z = bf16rne(v.z); l.z = bf16rne(v.z - b2f(h.z));
        h.w = bf16rne(v.w); l.w = bf16rne(v.w - b2f(h.w));
        ((ushort4*)hi)[i] = h;
        ((ushort4*)lo)[i] = l;
    }
}

// ---------------- VQ ----------------
template <bool YB16>
__global__ __launch_bounds__(256) void vq_kernel(
    const float* __restrict__ h, const float* __restrict__ cb,
    const uint32_t* __restrict__ nlp,
    float* __restrict__ yf, uint16_t* __restrict__ yb,
    uint32_t ka0, uint32_t ka1, uint32_t kb0, uint32_t kb1,
    uint32_t kc0, uint32_t kc1, uint32_t kd0, uint32_t kd1) {
    __shared__ float xs[DCODE];
    __shared__ float sred[NCODE];
    __shared__ int sidx[NCODE];

    const int b = blockIdx.x;
    const int chunk = blockIdx.y;
    const int c = threadIdx.x;

    if (c < DCODE) xs[c] = h[(size_t)b * NCODE + chunk * DCODE + c];
    __syncthreads();

    float dot = 0.f, x2 = 0.f, c2 = 0.f;
    const float* crow = cb + c * DCODE;
#pragma unroll 8
    for (int i = 0; i < DCODE; ++i) {
        float xv = xs[i], cv = crow[i];
        dot = fmaf(xv, cv, dot);
        x2 = fmaf(xv, xv, x2);
        c2 = fmaf(cv, cv, c2);
    }
    float d = sqrtf(fmaxf(x2 - 2.f * dot + c2, 0.f));
    float logit = -d * 0.125f;

    sred[c] = logit;
    __syncthreads();
    for (int s = 128; s > 0; s >>= 1) {
        if (c < s) sred[c] = fmaxf(sred[c], sred[c + s]);
        __syncthreads();
    }
    float mx = sred[0];
    __syncthreads();
    float e = expf(logit - mx);
    sred[c] = e;
    __syncthreads();
    for (int s = 128; s > 0; s >>= 1) {
        if (c < s) sred[c] = sred[c] + sred[c + s];
        __syncthreads();
    }
    float ssum = sred[0];
    __syncthreads();
    float r = e / ssum;

    int vi = (int)nlp[0];
    float noise_level = (vi >= -1000000 && vi <= 1000000)
                            ? (float)vi
                            : __uint_as_float(nlp[0]);

    // partitionable threefry: bits = o1 ^ o2, counter = (0, lin)
    uint32_t lin = (uint32_t)b * 256u + (uint32_t)c;
    uint32_t k0 = chunk == 0 ? ka0 : chunk == 1 ? kb0 : chunk == 2 ? kc0 : kd0;
    uint32_t k1 = chunk == 0 ? ka1 : chunk == 1 ? kb1 : chunk == 2 ? kc1 : kd1;
    uint32_t x0 = 0u, x1 = lin;
    tf2x32(k0, k1, x0, x1);
    uint32_t bits = x0 ^ x1;
    float noise = __uint_as_float((bits >> 9) | 0x3f800000u) - 1.0f;

    float score = r - noise_level * noise;

    sred[c] = score;
    sidx[c] = c;
    __syncthreads();
    for (int s = 128; s > 0; s >>= 1) {
        if (c < s) {
            float ov = sred[c + s];
            int oi = sidx[c + s];
            if (ov > sred[c] || (ov == sred[c] && oi < sidx[c])) {
                sred[c] = ov;
                sidx[c] = oi;
            }
        }
        __syncthreads();
    }
    int best = sidx[0];

    if (c < DCODE) {
        float v = cb[(size_t)best * DCODE + c];
        if constexpr (YB16)
            yb[(size_t)b * NCODE + chunk * DCODE + c] = bf16rne(v);
        else
            yf[(size_t)b * NCODE + chunk * DCODE + c] = v;
    }
}

// ---------------- fallback f32 GEMM (verified Round-4 path) ----------------
template <int BM, int BN, bool TANH>
__global__ __launch_bounds__(256) void gemm_f32(const float* __restrict__ A,
                                                const float* __restrict__ W,
                                                float* __restrict__ C,
                                                int M, int N, int K) {
    constexpr int BK = 16;
    constexpr int TM = BM / 16, TN = BN / 16;
    constexpr int GM = TM / 4, GN = TN / 4;
    constexpr int PA = BM + 4, PB = BN + 4;
    __shared__ float As[BK][PA];
    __shared__ float Bs[BK][PB];

    const int tid = threadIdx.x;
    const int tx = tid & 15, ty = tid >> 4;
    const size_t bm = (size_t)blockIdx.y * BM;
    const size_t bn = (size_t)blockIdx.x * BN;

    float acc[TM][TN];
#pragma unroll
    for (int i = 0; i < TM; ++i)
#pragma unroll
        for (int j = 0; j < TN; ++j) acc[i][j] = 0.f;

    for (int k0 = 0; k0 < K; k0 += BK) {
#pragma unroll
        for (int i = 0; i < BM * BK / 4 / 256; ++i) {
            int f4 = tid + i * 256;
            int row = f4 >> 2;
            int c4 = f4 & 3;
            float4 v = *reinterpret_cast<const float4*>(A + (bm + row) * K + k0 + c4 * 4);
            As[c4 * 4 + 0][row] = v.x;
            As[c4 * 4 + 1][row] = v.y;
            As[c4 * 4 + 2][row] = v.z;
            As[c4 * 4 + 3][row] = v.w;
        }
#pragma unroll
        for (int i = 0; i < BK * BN / 4 / 256; ++i) {
            int f4 = tid + i * 256;
            int row = f4 / (BN / 4);
            int c4 = f4 % (BN / 4);
            *reinterpret_cast<float4*>(&Bs[row][c4 * 4]) =
                *reinterpret_cast<const float4*>(W + (size_t)(k0 + row) * N + bn + c4 * 4);
        }
        __syncthreads();
#pragma unroll
        for (int k = 0; k < BK; ++k) {
            float4 af[GM], bf[GN];
#pragma unroll
            for (int g = 0; g < GM; ++g)
                af[g] = *reinterpret_cast<const float4*>(&As[k][g * 64 + ty * 4]);
#pragma unroll
            for (int g = 0; g < GN; ++g)
                bf[g] = *reinterpret_cast<const float4*>(&Bs[k][g * 64 + tx * 4]);
#pragma unroll
            for (int gm = 0; gm < GM; ++gm) {
                const float* ap = &af[gm].x;
#pragma unroll
                for (int r = 0; r < 4; ++r) {
#pragma unroll
                    for (int gn = 0; gn < GN; ++gn) {
                        const float* bp = &bf[gn].x;
#pragma unroll
                        for (int c = 0; c < 4; ++c)
                            acc[gm * 4 + r][gn * 4 + c] =
                                fmaf(ap[r], bp[c], acc[gm * 4 + r][gn * 4 + c]);
                    }
                }
            }
        }
        __syncthreads();
    }

#pragma unroll
    for (int gm = 0; gm < GM; ++gm) {
#pragma unroll
        for (int r = 0; r < 4; ++r) {
            size_t row = bm + gm * 64 + ty * 4 + r;
#pragma unroll
            for (int gn = 0; gn < GN; ++gn) {
                size_t col = bn + gn * 64 + tx * 4;
                float4 bias = *reinterpret_cast<const float4*>(W + (size_t)K * N + col);
                float4 o;
                o.x = acc[gm * 4 + r][gn * 4 + 0] + bias.x;
                o.y = acc[gm * 4 + r][gn * 4 + 1] + bias.y;
                o.z = acc[gm * 4 + r][gn * 4 + 2] + bias.z;
                o.w = acc[gm * 4 + r][gn * 4 + 3] + bias.w;
                if (TANH) {
                    o.x = tanhf(o.x); o.y = tanhf(o.y);
                    o.z = tanhf(o.z); o.w = tanhf(o.w);
                }
                *reinterpret_cast<float4*>(C + row * N + col) = o;
            }
        }
    }
}

// ---------------- launch ----------------
extern "C" void kernel_launch(void* const* d_in, const int* in_sizes, int n_in,
                              void* d_out, int out_size, void* d_ws, size_t ws_size,
                              hipStream_t stream) {
    const float* x   = (const float*)d_in[0];
    const float* w1e = (const float*)d_in[1];
    const float* w2e = (const float*)d_in[2];
    const float* w1d = (const float*)d_in[3];
    const float* w2d = (const float*)d_in[4];
    const float* cb1 = (const float*)d_in[5];
    const uint32_t* nl = (const uint32_t*)d_in[9];
    float* out = (float*)d_out;

    const int M = in_sizes[0] / IMG_DIM;  // 4096

    // VQ keys (host-side fold_in)
    uint32_t ks[4][2];
    for (int j = 1; j <= 4; ++j) {
        uint32_t a = 0u, bb = (uint32_t)j;
        tf2x32(0u, 12345u, a, bb);
        ks[j - 1][0] = a;
        ks[j - 1][1] = bb;
    }

    // ws layout (bytes), with time-aliasing:
    const size_t o_h1hi  = 0;           // 134217728  (later: h2 bf16)
    const size_t o_h1lo  = 134217728;   // 134217728
    const size_t o_w1ehi = 268435456;   // 100663296  (later: Wt2d)
    const size_t o_w1elo = 369098752;   // 100663296  (later: Wt1d)
    const size_t o_w2ehi = 469762048;   // 8388608
    const size_t o_w2elo = 478150656;   // 8388608
    const size_t o_h     = 486539264;   // 4194304
    const size_t o_y     = 490733568;   // 2097152
    const size_t o_xhi   = 492830720;   // 25165824
    const size_t o_xlo   = 517996544;   // 25165824
    const size_t NEED    = 543162368;

    uint8_t* ws = (uint8_t*)d_ws;

    if (ws_size >= NEED) {
        uint16_t* h1hi  = (uint16_t*)(ws + o_h1hi);
        uint16_t* h1lo  = (uint16_t*)(ws + o_h1lo);
        uint16_t* w1ehi = (uint16_t*)(ws + o_w1ehi);
        uint16_t* w1elo = (uint16_t*)(ws + o_w1elo);
        uint16_t* w2ehi = (uint16_t*)(ws + o_w2ehi);
        uint16_t* w2elo = (uint16_t*)(ws + o_w2elo);
        float*    hbuf  = (float*)(ws + o_h);
        uint16_t* ybuf  = (uint16_t*)(ws + o_y);
        uint16_t* xhi   = (uint16_t*)(ws + o_xhi);
        uint16_t* xlo   = (uint16_t*)(ws + o_xlo);
        uint16_t* wt2d  = (uint16_t*)(ws + o_w1ehi);  // alias after E1
        uint16_t* wt1d  = (uint16_t*)(ws + o_w1elo);  // alias after E1
        uint16_t* h2    = (uint16_t*)(ws + o_h1hi);   // alias after E2

        // prep
        split_x<<<2048, 256, 0, stream>>>(x, xhi, xlo, (size_t)M * IMG_DIM / 4);
        wconv<true><<<dim3(IMG_DIM / 32, HID / 32), 256, 0, stream>>>(w1e, w1ehi, w1elo, IMG_DIM, HID);
        wconv<true><<<dim3(HID / 32, NCODE / 32), 256, 0, stream>>>(w2e, w2ehi, w2elo, HID, NCODE);
        // E1: h1 = tanh(x @ w1e + b) -> bf16 hi/lo
        gemm_mfma<3, true><<<dim3(HID / 128, M / 128), 256, 0, stream>>>(
            xhi, xlo, w1ehi, w1elo, w1e + (size_t)IMG_DIM * HID,
            nullptr, nullptr, h1hi, h1lo, M, HID, IMG_DIM);
        // decoder weight conversions (into regions freed by E1)
        wconv<false><<<dim3(HID / 32, IMG_DIM / 32), 256, 0, stream>>>(w2d, wt2d, nullptr, HID, IMG_DIM);
        wconv<false><<<dim3(NCODE / 32, HID / 32), 256, 0, stream>>>(w1d, wt1d, nullptr, NCODE, HID);
        // E2: h = tanh(h1 @ w2e + b) -> f32
        gemm_mfma<1, true><<<dim3(NCODE / 128, M / 128), 256, 0, stream>>>(
            h1hi, h1lo, w2ehi, w2elo, w2e + (size_t)HID * NCODE,
            hbuf, nullptr, nullptr, nullptr, M, NCODE, HID);
        // VQ -> y bf16
        vq_kernel<true><<<dim3(M, 4), 256, 0, stream>>>(
            hbuf, cb1, nl, nullptr, ybuf,
            ks[0][0], ks[0][1], ks[1][0], ks[1][1],
            ks[2][0], ks[2][1], ks[3][0], ks[3][1]);
        // D1: h2 = tanh(y @ w1d + b) -> bf16
        gemm_mfma<2, false><<<dim3(HID / 128, M / 128), 256, 0, stream>>>(
            ybuf, nullptr, wt1d, nullptr, w1d + (size_t)NCODE * HID,
            nullptr, h2, nullptr, nullptr, M, HID, NCODE);
        // D2: out = h2 @ w2d + b -> f32
        gemm_mfma<0, false><<<dim3(IMG_DIM / 128, M / 128), 256, 0, stream>>>(
            h2, nullptr, wt2d, nullptr, w2d + (size_t)HID * IMG_DIM,
            out, nullptr, nullptr, nullptr, M, IMG_DIM, HID);
    } else {
        // fallback: verified f32 path
        float* h1 = (float*)d_ws;
        float* h  = h1 + (size_t)M * HID;
        float* yb = h + (size_t)M * NCODE;
        {
            dim3 g(HID / 128, M / 128);
            gemm_f32<128, 128, true><<<g, 256, 0, stream>>>(x, w1e, h1, M, HID, IMG_DIM);
        }
        {
            dim3 g(NCODE / 64, M / 64);
            gemm_f32<64, 64, true><<<g, 256, 0, stream>>>(h1, w2e, h, M, NCODE, HID);
        }
        vq_kernel<false><<<dim3(M, 4), 256, 0, stream>>>(
            h, cb1, nl, yb, nullptr,
            ks[0][0], ks[0][1], ks[1][0], ks[1][1],
            ks[2][0], ks[2][1], ks[3][0], ks[3][1]);
        {
            dim3 g(HID / 128, M / 128);
            gemm_f32<128, 128, true><<<g, 256, 0, stream>>>(yb, w1d, h1, M, HID, NCODE);
        }
        {
            dim3 g(IMG_DIM / 128, M / 128);
            gemm_f32<128, 128, false><<<g, 256, 0, stream>>>(h1, w2d, out, M, IMG_DIM, HID);
        }
    }
}